// Round 7
// baseline (89.001 us; speedup 1.0000x reference)
//
#include <hip/hip_runtime.h>

typedef _Float16 f16;
typedef __attribute__((ext_vector_type(8))) _Float16 f16x8;
typedef __attribute__((ext_vector_type(4))) _Float16 f16x4;
typedef __attribute__((ext_vector_type(4))) float f32x4;

#define MFMA16(a, b, c) __builtin_amdgcn_mfma_f32_16x16x32_f16(a, b, c, 0, 0, 0)

#define B_N 16384
#define E_N 9
#define TILE 32
#define NTILE_MAX 520  // = 8*65, XCD swizzle exact; 520 <= 1024 slots -> single round
#define THREADS 512

#define D_IN 512
#define D_H1 512
#define D_H2 256
#define D_H3 128
#define D_A 16

// Weight image: per (e,w) 104 contiguous 1KB B-fragment records in exact
// consumption order. Record r at ((e*8+w)*104 + r)*1024; lane l's 16B at +l*16.
//   r 0..63   L1: i=r:    n=w*64+((i>>5)&1)*32+(i&1)*16+ln, k=((i>>2)&7)*64+((i>>1)&1)*32+lg*8
//   r 64..95  L2: j=r-64: n=w*32+(j&1)*16+ln,               k=(j>>2)*64+((j>>1)&1)*32+lg*8
//   r 96..103 L3: j=r-96: n=w*16+ln,                        k=(j>>1)*64+(j&1)*32+lg*8
// L4: plain [16n][128k] per expert (4KB) at O4B.
#define RPW 104
#define O4B 7667712    // 9*8*104*1024
#define WPL_BYTES 7704576
#define WSLOTS (WPL_BYTES / 16)   // 481536 = 1881 * 256

#define IDX_OFF 64
#define WP_OFF 131584
#define WS_NEED (WP_OFF + (size_t)WPL_BYTES)

// LDS (bytes) -- 32KB total -> 4 blocks/CU (with <=64 VGPR -> 32 waves/CU)
#define XS_OFF 0        // x fp16 [32][512] stride 1024, swz ((row&15)<<4); h1 overlays after L1
#define H2_OFF 0        // h2 [32][256] stride 512 (overlays h1 rows 0..31 low half)
#define H3_OFF 16384    // h3 [32][128] stride 256 (overlays h1 upper half)
#define LDS_BYTES 32768

// ---------------- prep: block 0 = bucket, blocks 1.. = weight convert ----------------

__global__ void k_prep(const int* __restrict__ pos,
                       const float* __restrict__ W1, const float* __restrict__ W2,
                       const float* __restrict__ W3, const float* __restrict__ W4,
                       int* __restrict__ hdr, int* __restrict__ idx,
                       char* __restrict__ wp) {
  if (blockIdx.x == 0) {
    __shared__ int cnt[E_N], cur[E_N];
    __shared__ int flag_s;
    const int t = threadIdx.x;  // 256
    if (t < E_N) cnt[t] = 0;
    if (t == 0) {
      int nz = 0;
      for (int i = 0; i < 64; ++i) nz |= pos[2 * i + 1];
      flag_s = (nz == 0) ? 1 : 0;  // int64 layout if all high words zero
    }
    __syncthreads();
    const bool f64 = flag_s != 0;
#pragma unroll 4
    for (int k = 0; k < 64; ++k) {
      int i = k * 256 + t;
      long long v = f64 ? ((const long long*)pos)[i] : (long long)pos[i];
      v = v < 0 ? 0 : (v > 8 ? 8 : v);
      atomicAdd(&cnt[(int)v], 1);
    }
    __syncthreads();
    if (t == 0) {
      int acc = 0;
      for (int ee = 0; ee < E_N; ++ee) { cur[ee] = acc; acc += cnt[ee]; }
    }
    if (t < E_N) hdr[8 + t] = cnt[t];
    __syncthreads();
#pragma unroll 4
    for (int k = 0; k < 64; ++k) {
      int i = k * 256 + t;
      long long v = f64 ? ((const long long*)pos)[i] : (long long)pos[i];
      v = v < 0 ? 0 : (v > 8 ? 8 : v);
      int slot = atomicAdd(&cur[(int)v], 1);
      idx[slot] = i;
    }
    return;
  }

  int slot = (blockIdx.x - 1) * 256 + threadIdx.x;
  if (slot >= WSLOTS) return;
  long addr = (long)slot << 4;
  int lane = slot & 63;
  int lg = lane >> 4, ln = lane & 15;
  const float* src;
  if (addr < O4B) {
    int rec = (int)(addr >> 10);
    int f = rec % RPW;
    int ew = rec / RPW;
    int w = ew & 7, e = ew >> 3;
    if (f < 64) {
      int n = w * 64 + ((f >> 5) & 1) * 32 + (f & 1) * 16 + ln;
      int k = ((f >> 2) & 7) * 64 + ((f >> 1) & 1) * 32 + lg * 8;
      src = W1 + ((long)e * D_H1 + n) * D_IN + k;
    } else if (f < 96) {
      int j = f - 64;
      int n = w * 32 + (j & 1) * 16 + ln;
      int k = (j >> 2) * 64 + ((j >> 1) & 1) * 32 + lg * 8;
      src = W2 + ((long)e * D_H2 + n) * D_H1 + k;
    } else {
      int j = f - 96;
      int n = w * 16 + ln;
      int k = (j >> 1) * 64 + (j & 1) * 32 + lg * 8;
      src = W3 + ((long)e * D_H3 + n) * D_H2 + k;
    }
  } else {
    long rel = addr - O4B;
    int e = (int)(rel >> 12);
    int r2 = (int)(rel & 4095);
    int s = r2 >> 4, n = s >> 4, k16 = s & 15;
    src = W4 + ((long)e * D_A + n) * D_H3 + k16 * 8;
  }
  float4 a = *(const float4*)src;
  float4 b = *(const float4*)(src + 4);
  f16x8 h;
  h[0] = (f16)a.x; h[1] = (f16)a.y; h[2] = (f16)a.z; h[3] = (f16)a.w;
  h[4] = (f16)b.x; h[5] = (f16)b.y; h[6] = (f16)b.z; h[7] = (f16)b.w;
  *(f16x8*)(wp + addr) = h;
}

// ---------------- fused MLP ----------------

// A-fragment (16x16x32): lane m = rowoff + (l&15), k-bytes q + (l>>4)*16, XOR swz
__device__ __forceinline__ f16x8 afrag(const char* base, int strideB, int rowoff,
                                       int kbytes, int lane) {
  int m = rowoff + (lane & 15);
  int q = kbytes + ((lane >> 4) * 16);
  return *(const f16x8*)(base + m * strideB + (q ^ ((m & 15) << 4)));
}

__device__ __forceinline__ f16x8 ldfrag(const char* wb, int f, int lane) {
  return *(const f16x8*)(wb + (long)f * 1024 + lane * 16);
}

__launch_bounds__(THREADS, 8)  // force <=64 VGPR -> 8 waves/SIMD -> 4 blocks/CU
__global__ void k_mlp(const float* __restrict__ x,
                      const float* __restrict__ b1, const float* __restrict__ b2,
                      const float* __restrict__ b3, const float* __restrict__ b4,
                      const int* __restrict__ hdr, const int* __restrict__ idx,
                      const char* __restrict__ wp, float* __restrict__ out) {
  __shared__ __align__(16) char lds[LDS_BYTES];

  int b = blockIdx.x;
  int bswz = (b & 7) * (NTILE_MAX / 8) + (b >> 3);  // bijective, 520 = 8*65

  const int* counts = hdr + 8;
  int e = -1, tile = 0, base = 0, ne = 0;
  {
    int acc = 0, off = 0;
    for (int ee = 0; ee < E_N; ++ee) {
      int n = counts[ee];
      int nt = (n + TILE - 1) / TILE;
      if (bswz < acc + nt) { e = ee; tile = bswz - acc; ne = n; base = off; break; }
      acc += nt; off += n;
    }
  }
  if (e < 0) return;
  const int rvalid = min(TILE, ne - tile * TILE);
  const int row0 = base + tile * TILE;

  const int t = threadIdx.x;
  const int lane = t & 63;
  const int wid = t >> 6;
  const int lg = lane >> 4;
  const int ln = lane & 15;

  const char* wb = wp + ((long)(e * 8 + wid) * RPW << 10);
  const char* wpe4 = wp + O4B + (long)e * 4096;

  // prefetch queue over the flat 104-record stream
  f16x8 Q[4];
  Q[0] = ldfrag(wb, 0, lane);
  Q[1] = ldfrag(wb, 1, lane);
  Q[2] = ldfrag(wb, 2, lane);
  Q[3] = ldfrag(wb, 3, lane);

  // ---- stage x tile as fp16, XOR-swizzled ----
  const float4* x4 = (const float4*)x;
  for (int u = t; u < TILE * (D_IN / 4); u += THREADS) {
    int s = u >> 7, c4 = u & 127;
    float4 v = make_float4(0.f, 0.f, 0.f, 0.f);
    if (s < rvalid) v = x4[(long)idx[row0 + s] * (D_IN / 4) + c4];
    f16x4 h;
    h[0] = (f16)v.x; h[1] = (f16)v.y; h[2] = (f16)v.z; h[3] = (f16)v.w;
    *(f16x4*)(lds + XS_OFF + s * 1024 + ((c4 * 8) ^ ((s & 15) << 4))) = h;
  }
  __syncthreads();

  // ---------------- L1: x @ W1^T -> h1 in registers ----------------
  f16x8 h1r[2][2];  // [colhalf][m], elems nf*4+j
  {
    f32x4 acc[2][2];
#pragma unroll
    for (int g = 0; g < 16; ++g) {
      const int kb = g & 7, h = g >> 3;
      if (kb == 0) {
#pragma unroll
        for (int m = 0; m < 2; ++m)
#pragma unroll
          for (int nf = 0; nf < 2; ++nf) acc[m][nf] = (f32x4){0.f, 0.f, 0.f, 0.f};
      }
      __builtin_amdgcn_s_setprio(1);
#pragma unroll
      for (int kc = 0; kc < 2; ++kc) {
        f16x8 A0 = afrag(lds + XS_OFF, 1024, 0, kb * 128 + kc * 64, lane);
        f16x8 A1 = afrag(lds + XS_OFF, 1024, 16, kb * 128 + kc * 64, lane);
#pragma unroll
        for (int nf = 0; nf < 2; ++nf) {
          const int i = g * 4 + kc * 2 + nf;
          acc[0][nf] = MFMA16(A0, Q[i & 3], acc[0][nf]);
          acc[1][nf] = MFMA16(A1, Q[i & 3], acc[1][nf]);
          Q[i & 3] = ldfrag(wb, i + 4, lane);  // i<=63 -> i+4<=67
        }
      }
      __builtin_amdgcn_s_setprio(0);
      if (kb == 7) {
#pragma unroll
        for (int nf = 0; nf < 2; ++nf) {
          float bias = b1[e * D_H1 + wid * 64 + h * 32 + nf * 16 + ln];
#pragma unroll
          for (int m = 0; m < 2; ++m)
#pragma unroll
            for (int j = 0; j < 4; ++j) {
              float v = acc[m][nf][j] + bias;
              h1r[h][m][nf * 4 + j] = (f16)(v > 0.f ? v : 0.f);
            }
        }
      }
    }
  }
  __syncthreads();  // all L1 reads of x done; x region dead

  // write h1 (fp16, swizzled) into the x region
#pragma unroll
  for (int h = 0; h < 2; ++h)
#pragma unroll
    for (int m = 0; m < 2; ++m)
#pragma unroll
      for (int nf = 0; nf < 2; ++nf)
#pragma unroll
        for (int j = 0; j < 4; ++j) {
          int rw = m * 16 + lg * 4 + j;
          int n = wid * 64 + h * 32 + nf * 16 + ln;
          *(f16*)(lds + XS_OFF + rw * 1024 + ((n * 2) ^ ((rw & 15) << 4))) =
              h1r[h][m][nf * 4 + j];
        }
  __syncthreads();

  // ---------------- L2: h1 @ W2^T (frags 64..95) ----------------
  f16x8 h2r[2];  // [m], elems nf*4+j
  {
    f32x4 acc[2][2];
#pragma unroll
    for (int m = 0; m < 2; ++m)
#pragma unroll
      for (int nf = 0; nf < 2; ++nf) acc[m][nf] = (f32x4){0.f, 0.f, 0.f, 0.f};
#pragma unroll
    for (int g = 0; g < 8; ++g) {
      __builtin_amdgcn_s_setprio(1);
#pragma unroll
      for (int kc = 0; kc < 2; ++kc) {
        f16x8 A0 = afrag(lds + XS_OFF, 1024, 0, g * 128 + kc * 64, lane);
        f16x8 A1 = afrag(lds + XS_OFF, 1024, 16, g * 128 + kc * 64, lane);
#pragma unroll
        for (int nf = 0; nf < 2; ++nf) {
          const int i = 64 + g * 4 + kc * 2 + nf;
          acc[0][nf] = MFMA16(A0, Q[i & 3], acc[0][nf]);
          acc[1][nf] = MFMA16(A1, Q[i & 3], acc[1][nf]);
          Q[i & 3] = ldfrag(wb, i + 4, lane);  // i<=95 -> i+4<=99
        }
      }
      __builtin_amdgcn_s_setprio(0);
    }
#pragma unroll
    for (int nf = 0; nf < 2; ++nf) {
      float bias = b2[e * D_H2 + wid * 32 + nf * 16 + ln];
#pragma unroll
      for (int m = 0; m < 2; ++m)
#pragma unroll
        for (int j = 0; j < 4; ++j) {
          float v = acc[m][nf][j] + bias;
          h2r[m][nf * 4 + j] = (f16)(v > 0.f ? v : 0.f);
        }
    }
  }
  __syncthreads();  // all L2 reads of h1 done

  // write h2 [32][256] stride 512 into [0,16K)
#pragma unroll
  for (int m = 0; m < 2; ++m)
#pragma unroll
    for (int nf = 0; nf < 2; ++nf)
#pragma unroll
      for (int j = 0; j < 4; ++j) {
        int rw = m * 16 + lg * 4 + j;
        int n = wid * 32 + nf * 16 + ln;
        *(f16*)(lds + H2_OFF + rw * 512 + ((n * 2) ^ ((rw & 15) << 4))) =
            h2r[m][nf * 4 + j];
      }
  __syncthreads();

  // ---------------- L3: h2 @ W3^T (frags 96..103) ----------------
  {
    f32x4 acc3[2];
    acc3[0] = (f32x4){0.f, 0.f, 0.f, 0.f};
    acc3[1] = (f32x4){0.f, 0.f, 0.f, 0.f};
#pragma unroll
    for (int g = 0; g < 4; ++g) {
      __builtin_amdgcn_s_setprio(1);
#pragma unroll
      for (int kc = 0; kc < 2; ++kc) {
        const int i = 96 + g * 2 + kc;
        f16x8 A0 = afrag(lds + H2_OFF, 512, 0, g * 128 + kc * 64, lane);
        f16x8 A1 = afrag(lds + H2_OFF, 512, 16, g * 128 + kc * 64, lane);
        acc3[0] = MFMA16(A0, Q[i & 3], acc3[0]);
        acc3[1] = MFMA16(A1, Q[i & 3], acc3[1]);
        if (i < 100) Q[i & 3] = ldfrag(wb, i + 4, lane);
      }
      __builtin_amdgcn_s_setprio(0);
    }
    int n = wid * 16 + ln;
    float bias = b3[e * D_H3 + n];
    // write h3 [32][128] stride 256 into [16K,24K) (disjoint from h2)
#pragma unroll
    for (int m = 0; m < 2; ++m)
#pragma unroll
      for (int j = 0; j < 4; ++j) {
        float v = acc3[m][j] + bias;
        v = v > 0.f ? v : 0.f;
        int rw = m * 16 + lg * 4 + j;
        *(f16*)(lds + H3_OFF + rw * 256 + ((n * 2) ^ ((rw & 15) << 4))) = (f16)v;
      }
  }
  __syncthreads();

  // ---------------- L4 + softmax (waves 0,1) ----------------
  if (wid < 2) {
    f32x4 a4 = (f32x4){0.f, 0.f, 0.f, 0.f};
#pragma unroll
    for (int kc = 0; kc < 4; ++kc) {
      f16x8 Bv = *(const f16x8*)(wpe4 + ln * 256 + kc * 64 + lg * 16);
      f16x8 Av = afrag(lds + H3_OFF, 256, wid * 16, kc * 64, lane);
      a4 = MFMA16(Av, Bv, a4);
    }
    float bias = b4[e * D_A + ln];
#pragma unroll
    for (int j = 0; j < 4; ++j) {
      float v = a4[j] + bias;
      float mx = v;
      for (int msk = 8; msk >= 1; msk >>= 1) mx = fmaxf(mx, __shfl_xor(mx, msk));
      float pe = expf(v - mx);
      float sm = pe;
      for (int msk = 8; msk >= 1; msk >>= 1) sm += __shfl_xor(sm, msk);
      int rl = wid * 16 + lg * 4 + j;
      if (rl < rvalid) out[(long)idx[row0 + rl] * D_A + ln] = pe / sm;
    }
  }
}

// ---------------- host ----------------

extern "C" void kernel_launch(void* const* d_in, const int* in_sizes, int n_in,
                              void* d_out, int out_size, void* d_ws, size_t ws_size,
                              hipStream_t stream) {
  const float* x  = (const float*)d_in[0];
  const int* pos  = (const int*)d_in[1];
  const float* W1 = (const float*)d_in[2];
  const float* b1 = (const float*)d_in[3];
  const float* W2 = (const float*)d_in[4];
  const float* b2 = (const float*)d_in[5];
  const float* W3 = (const float*)d_in[6];
  const float* b3 = (const float*)d_in[7];
  const float* W4 = (const float*)d_in[8];
  const float* b4 = (const float*)d_in[9];
  float* out = (float*)d_out;

  int* hdr = (int*)d_ws;
  int* idx = hdr + IDX_OFF;
  char* wp = (char*)d_ws + WP_OFF;

  hipLaunchKernelGGL(k_prep, dim3(1 + WSLOTS / 256), dim3(256), 0, stream,
                     pos, W1, W2, W3, W4, hdr, idx, wp);
  hipLaunchKernelGGL(k_mlp, dim3(NTILE_MAX), dim3(THREADS), 0, stream,
                     x, b1, b2, b3, b4, hdr, idx, wp, out);
}

// Round 8
// 81.306 us; speedup vs baseline: 1.0946x; 1.0946x over previous
//
#include <hip/hip_runtime.h>

typedef _Float16 f16;
typedef __attribute__((ext_vector_type(8))) _Float16 f16x8;
typedef __attribute__((ext_vector_type(4))) _Float16 f16x4;
typedef __attribute__((ext_vector_type(4))) float f32x4;

#define MFMA16(a, b, c) __builtin_amdgcn_mfma_f32_16x16x32_f16(a, b, c, 0, 0, 0)

#define B_N 16384
#define E_N 9
#define TILE 32
#define NTILE_MAX 520  // = 8*65; 520 <= 768 slots (3 blocks/CU) -> single round
#define THREADS 512

#define D_IN 512
#define D_H1 512
#define D_H2 256
#define D_H3 128
#define D_A 16

// Weight image: per (e,w) 104 contiguous 1KB B-fragment records in exact
// consumption order (identical to round 6). Record r at ((e*8+w)*104+r)*1024.
#define RPW 104
#define O4B 7667712
#define WPL_BYTES 7704576
#define WSLOTS (WPL_BYTES / 16)

#define IDX_OFF 64
#define WP_OFF 131584
#define WS_NEED (WP_OFF + (size_t)WPL_BYTES)

// LDS (bytes) -- 48KB -> 3 blocks/CU.
// x   [32][1024B] at 0..32K (swz (row&15)<<4)
// h1 bank0 (cols bit5=0) [32][512B] at 32K..48K  (dedicated; direct write in L1)
// h1 bank1 (cols bit5=1) [32][512B] at 0..16K    (overlays x after L1; staged)
// h2  [32][512B] at 16K..32K (overlays x tail; direct write during L2)
// h3  [32][256B] at 32K..40K (overlays bank0; direct write during L3)
#define XS_OFF 0
#define B1H_OFF 0
#define H2_OFF 16384
#define B0H_OFF 32768
#define H3_OFF 32768
#define LDS_BYTES 49152

// ---------------- prep: block 0 = bucket, blocks 1.. = weight convert ----------------

__global__ void k_prep(const int* __restrict__ pos,
                       const float* __restrict__ W1, const float* __restrict__ W2,
                       const float* __restrict__ W3, const float* __restrict__ W4,
                       int* __restrict__ hdr, int* __restrict__ idx,
                       char* __restrict__ wp) {
  if (blockIdx.x == 0) {
    __shared__ int cnt[E_N], cur[E_N];
    __shared__ int flag_s;
    const int t = threadIdx.x;  // 256
    if (t < E_N) cnt[t] = 0;
    if (t == 0) {
      int nz = 0;
      for (int i = 0; i < 64; ++i) nz |= pos[2 * i + 1];
      flag_s = (nz == 0) ? 1 : 0;  // int64 layout if all high words zero
    }
    __syncthreads();
    const bool f64 = flag_s != 0;
#pragma unroll 4
    for (int k = 0; k < 64; ++k) {
      int i = k * 256 + t;
      long long v = f64 ? ((const long long*)pos)[i] : (long long)pos[i];
      v = v < 0 ? 0 : (v > 8 ? 8 : v);
      atomicAdd(&cnt[(int)v], 1);
    }
    __syncthreads();
    if (t == 0) {
      int acc = 0;
      for (int ee = 0; ee < E_N; ++ee) { cur[ee] = acc; acc += cnt[ee]; }
    }
    if (t < E_N) hdr[8 + t] = cnt[t];
    __syncthreads();
#pragma unroll 4
    for (int k = 0; k < 64; ++k) {
      int i = k * 256 + t;
      long long v = f64 ? ((const long long*)pos)[i] : (long long)pos[i];
      v = v < 0 ? 0 : (v > 8 ? 8 : v);
      int slot = atomicAdd(&cur[(int)v], 1);
      idx[slot] = i;
    }
    return;
  }

  int slot = (blockIdx.x - 1) * 256 + threadIdx.x;
  if (slot >= WSLOTS) return;
  long addr = (long)slot << 4;
  int lane = slot & 63;
  int lg = lane >> 4, ln = lane & 15;
  const float* src;
  if (addr < O4B) {
    int rec = (int)(addr >> 10);
    int f = rec % RPW;
    int ew = rec / RPW;
    int w = ew & 7, e = ew >> 3;
    if (f < 64) {
      int n = w * 64 + ((f >> 5) & 1) * 32 + (f & 1) * 16 + ln;
      int k = ((f >> 2) & 7) * 64 + ((f >> 1) & 1) * 32 + lg * 8;
      src = W1 + ((long)e * D_H1 + n) * D_IN + k;
    } else if (f < 96) {
      int j = f - 64;
      int n = w * 32 + (j & 1) * 16 + ln;
      int k = (j >> 2) * 64 + ((j >> 1) & 1) * 32 + lg * 8;
      src = W2 + ((long)e * D_H2 + n) * D_H1 + k;
    } else {
      int j = f - 96;
      int n = w * 16 + ln;
      int k = (j >> 1) * 64 + (j & 1) * 32 + lg * 8;
      src = W3 + ((long)e * D_H3 + n) * D_H2 + k;
    }
  } else {
    long rel = addr - O4B;
    int e = (int)(rel >> 12);
    int r2 = (int)(rel & 4095);
    int s = r2 >> 4, n = s >> 4, k16 = s & 15;
    src = W4 + ((long)e * D_A + n) * D_H3 + k16 * 8;
  }
  float4 a = *(const float4*)src;
  float4 b = *(const float4*)(src + 4);
  f16x8 h;
  h[0] = (f16)a.x; h[1] = (f16)a.y; h[2] = (f16)a.z; h[3] = (f16)a.w;
  h[4] = (f16)b.x; h[5] = (f16)b.y; h[6] = (f16)b.z; h[7] = (f16)b.w;
  *(f16x8*)(wp + addr) = h;
}

// ---------------- fused MLP ----------------

// A-fragment (16x16x32): row m = rowoff + (l&15), k-bytes kbytes + (l>>4)*16, XOR swz
__device__ __forceinline__ f16x8 afrag(const char* base, int strideB, int rowoff,
                                       int kbytes, int lane) {
  int m = rowoff + (lane & 15);
  int q = kbytes + ((lane >> 4) * 16);
  return *(const f16x8*)(base + m * strideB + (q ^ ((m & 15) << 4)));
}

__device__ __forceinline__ f16x8 ldfrag(const char* wb, int f, int lane) {
  return *(const f16x8*)(wb + (long)f * 1024 + lane * 16);
}

__launch_bounds__(THREADS, 4)  // proven round-6 setting; natural demand ~64 VGPR
__global__ void k_mlp(const float* __restrict__ x,
                      const float* __restrict__ b1, const float* __restrict__ b2,
                      const float* __restrict__ b3, const float* __restrict__ b4,
                      const int* __restrict__ hdr, const int* __restrict__ idx,
                      const char* __restrict__ wp, float* __restrict__ out) {
  __shared__ __align__(16) char lds[LDS_BYTES];

  int b = blockIdx.x;
  int bswz = (b & 7) * (NTILE_MAX / 8) + (b >> 3);  // bijective, 520 = 8*65

  const int* counts = hdr + 8;
  int e = -1, tile = 0, base = 0, ne = 0;
  {
    int acc = 0, off = 0;
    for (int ee = 0; ee < E_N; ++ee) {
      int n = counts[ee];
      int nt = (n + TILE - 1) / TILE;
      if (bswz < acc + nt) { e = ee; tile = bswz - acc; ne = n; base = off; break; }
      acc += nt; off += n;
    }
  }
  if (e < 0) return;
  const int rvalid = min(TILE, ne - tile * TILE);
  const int row0 = base + tile * TILE;

  const int t = threadIdx.x;
  const int lane = t & 63;
  const int wid = t >> 6;
  const int lg = lane >> 4;
  const int ln = lane & 15;

  const char* wb = wp + ((long)(e * 8 + wid) * RPW << 10);
  const char* wpe4 = wp + O4B + (long)e * 4096;

  // prefetch queue over the flat 104-record stream
  f16x8 Q[4];
  Q[0] = ldfrag(wb, 0, lane);
  Q[1] = ldfrag(wb, 1, lane);
  Q[2] = ldfrag(wb, 2, lane);
  Q[3] = ldfrag(wb, 3, lane);

  // ---- stage x tile as fp16, XOR-swizzled ----
  const float4* x4 = (const float4*)x;
  for (int u = t; u < TILE * (D_IN / 4); u += THREADS) {
    int s = u >> 7, c4 = u & 127;
    float4 v = make_float4(0.f, 0.f, 0.f, 0.f);
    if (s < rvalid) v = x4[(long)idx[row0 + s] * (D_IN / 4) + c4];
    f16x4 h;
    h[0] = (f16)v.x; h[1] = (f16)v.y; h[2] = (f16)v.z; h[3] = (f16)v.w;
    *(f16x4*)(lds + XS_OFF + s * 1024 + ((c4 * 8) ^ ((s & 15) << 4))) = h;
  }
  __syncthreads();

  // ---------------- L1: x @ W1^T -> h1 banks ----------------
  // wave col group: n = wid*64 + h*32 + nf*16 + ln; bank = h; in-bank col
  // c = wid*32 + nf*16 + ln (byte 2c), row stride 512, swz (row&15)<<4.
  f16x8 st1[2];  // h=1 transient stage: [m], elems nf*4+j
  {
    f32x4 acc[2][2];
#pragma unroll
    for (int g = 0; g < 16; ++g) {
      const int kb = g & 7, h = g >> 3;
      if (kb == 0) {
#pragma unroll
        for (int m = 0; m < 2; ++m)
#pragma unroll
          for (int nf = 0; nf < 2; ++nf) acc[m][nf] = (f32x4){0.f, 0.f, 0.f, 0.f};
      }
      __builtin_amdgcn_s_setprio(1);
#pragma unroll
      for (int kc = 0; kc < 2; ++kc) {
        f16x8 A0 = afrag(lds + XS_OFF, 1024, 0, kb * 128 + kc * 64, lane);
        f16x8 A1 = afrag(lds + XS_OFF, 1024, 16, kb * 128 + kc * 64, lane);
#pragma unroll
        for (int nf = 0; nf < 2; ++nf) {
          const int i = g * 4 + kc * 2 + nf;
          acc[0][nf] = MFMA16(A0, Q[i & 3], acc[0][nf]);
          acc[1][nf] = MFMA16(A1, Q[i & 3], acc[1][nf]);
          Q[i & 3] = ldfrag(wb, i + 4, lane);  // i<=63 -> i+4<=67
        }
      }
      __builtin_amdgcn_s_setprio(0);
      if (kb == 7) {
        if (h == 0) {
          // bank0 is dedicated: write directly, no barrier
#pragma unroll
          for (int nf = 0; nf < 2; ++nf) {
            float bias = b1[e * D_H1 + wid * 64 + nf * 16 + ln];
            int cbyte = (wid * 32 + nf * 16 + ln) * 2;
#pragma unroll
            for (int m = 0; m < 2; ++m)
#pragma unroll
              for (int j = 0; j < 4; ++j) {
                float v = acc[m][nf][j] + bias;
                v = v > 0.f ? v : 0.f;
                int rw = m * 16 + lg * 4 + j;
                *(f16*)(lds + B0H_OFF + rw * 512 + (cbyte ^ ((rw & 15) << 4))) = (f16)v;
              }
          }
        } else {
          // stage h=1 in 8 VGPRs; bank1 overlays x -> must wait for all reads
#pragma unroll
          for (int nf = 0; nf < 2; ++nf) {
            float bias = b1[e * D_H1 + wid * 64 + 32 + nf * 16 + ln];
#pragma unroll
            for (int m = 0; m < 2; ++m)
#pragma unroll
              for (int j = 0; j < 4; ++j) {
                float v = acc[m][nf][j] + bias;
                st1[m][nf * 4 + j] = (f16)(v > 0.f ? v : 0.f);
              }
          }
        }
      }
    }
  }
  __syncthreads();  // all L1 reads of x done; x region dead

  // write h=1 half into bank1 (overlays x bytes 0..16K)
#pragma unroll
  for (int m = 0; m < 2; ++m)
#pragma unroll
    for (int nf = 0; nf < 2; ++nf) {
      int cbyte = (wid * 32 + nf * 16 + ln) * 2;
#pragma unroll
      for (int j = 0; j < 4; ++j) {
        int rw = m * 16 + lg * 4 + j;
        *(f16*)(lds + B1H_OFF + rw * 512 + (cbyte ^ ((rw & 15) << 4))) =
            st1[m][nf * 4 + j];
      }
    }
  __syncthreads();

  // ---------------- L2: h1 @ W2^T (frags 64..95) ----------------
  // A-read: k = g*64 + kc*32 + lg*8 -> bank = kc, byteoff = g*64 + lg*16
  {
    f32x4 acc[2][2];
#pragma unroll
    for (int m = 0; m < 2; ++m)
#pragma unroll
      for (int nf = 0; nf < 2; ++nf) acc[m][nf] = (f32x4){0.f, 0.f, 0.f, 0.f};
#pragma unroll
    for (int g = 0; g < 8; ++g) {
      __builtin_amdgcn_s_setprio(1);
#pragma unroll
      for (int kc = 0; kc < 2; ++kc) {
        const char* bank = lds + (kc ? B1H_OFF : B0H_OFF);
        f16x8 A0 = afrag(bank, 512, 0, g * 64, lane);
        f16x8 A1 = afrag(bank, 512, 16, g * 64, lane);
#pragma unroll
        for (int nf = 0; nf < 2; ++nf) {
          const int i = 64 + g * 4 + kc * 2 + nf;
          acc[0][nf] = MFMA16(A0, Q[i & 3], acc[0][nf]);
          acc[1][nf] = MFMA16(A1, Q[i & 3], acc[1][nf]);
          Q[i & 3] = ldfrag(wb, i + 4, lane);  // i<=95 -> i+4<=99
        }
      }
      __builtin_amdgcn_s_setprio(0);
    }
    // h2 [32][256] stride 512 at 16K..32K: disjoint from banks -> direct write
#pragma unroll
    for (int nf = 0; nf < 2; ++nf) {
      float bias = b2[e * D_H2 + wid * 32 + nf * 16 + ln];
      int cbyte = (wid * 32 + nf * 16 + ln) * 2;
#pragma unroll
      for (int m = 0; m < 2; ++m)
#pragma unroll
        for (int j = 0; j < 4; ++j) {
          float v = acc[m][nf][j] + bias;
          v = v > 0.f ? v : 0.f;
          int rw = m * 16 + lg * 4 + j;
          *(f16*)(lds + H2_OFF + rw * 512 + (cbyte ^ ((rw & 15) << 4))) = (f16)v;
        }
    }
  }
  __syncthreads();

  // ---------------- L3: h2 @ W3^T (frags 96..103) ----------------
  {
    f32x4 acc3[2];
    acc3[0] = (f32x4){0.f, 0.f, 0.f, 0.f};
    acc3[1] = (f32x4){0.f, 0.f, 0.f, 0.f};
#pragma unroll
    for (int g = 0; g < 4; ++g) {
      __builtin_amdgcn_s_setprio(1);
#pragma unroll
      for (int kc = 0; kc < 2; ++kc) {
        const int i = 96 + g * 2 + kc;
        f16x8 A0 = afrag(lds + H2_OFF, 512, 0, g * 128 + kc * 64, lane);
        f16x8 A1 = afrag(lds + H2_OFF, 512, 16, g * 128 + kc * 64, lane);
        acc3[0] = MFMA16(A0, Q[i & 3], acc3[0]);
        acc3[1] = MFMA16(A1, Q[i & 3], acc3[1]);
        if (i < 100) Q[i & 3] = ldfrag(wb, i + 4, lane);
      }
      __builtin_amdgcn_s_setprio(0);
    }
    int n = wid * 16 + ln;
    float bias = b3[e * D_H3 + n];
    // h3 [32][128] stride 256 at 32K..40K (bank0 dead after L2 barrier)
#pragma unroll
    for (int m = 0; m < 2; ++m)
#pragma unroll
      for (int j = 0; j < 4; ++j) {
        float v = acc3[m][j] + bias;
        v = v > 0.f ? v : 0.f;
        int rw = m * 16 + lg * 4 + j;
        *(f16*)(lds + H3_OFF + rw * 256 + ((n * 2) ^ ((rw & 15) << 4))) = (f16)v;
      }
  }
  __syncthreads();

  // ---------------- L4 + softmax (waves 0,1) ----------------
  if (wid < 2) {
    f32x4 a4 = (f32x4){0.f, 0.f, 0.f, 0.f};
#pragma unroll
    for (int kc = 0; kc < 4; ++kc) {
      f16x8 Bv = *(const f16x8*)(wpe4 + ln * 256 + kc * 64 + lg * 16);
      f16x8 Av = afrag(lds + H3_OFF, 256, wid * 16, kc * 64, lane);
      a4 = MFMA16(Av, Bv, a4);
    }
    float bias = b4[e * D_A + ln];
#pragma unroll
    for (int j = 0; j < 4; ++j) {
      float v = a4[j] + bias;
      float mx = v;
      for (int msk = 8; msk >= 1; msk >>= 1) mx = fmaxf(mx, __shfl_xor(mx, msk));
      float pe = expf(v - mx);
      float sm = pe;
      for (int msk = 8; msk >= 1; msk >>= 1) sm += __shfl_xor(sm, msk);
      int rl = wid * 16 + lg * 4 + j;
      if (rl < rvalid) out[(long)idx[row0 + rl] * D_A + ln] = pe / sm;
    }
  }
}

// ---------------- host ----------------

extern "C" void kernel_launch(void* const* d_in, const int* in_sizes, int n_in,
                              void* d_out, int out_size, void* d_ws, size_t ws_size,
                              hipStream_t stream) {
  const float* x  = (const float*)d_in[0];
  const int* pos  = (const int*)d_in[1];
  const float* W1 = (const float*)d_in[2];
  const float* b1 = (const float*)d_in[3];
  const float* W2 = (const float*)d_in[4];
  const float* b2 = (const float*)d_in[5];
  const float* W3 = (const float*)d_in[6];
  const float* b3 = (const float*)d_in[7];
  const float* W4 = (const float*)d_in[8];
  const float* b4 = (const float*)d_in[9];
  float* out = (float*)d_out;

  int* hdr = (int*)d_ws;
  int* idx = hdr + IDX_OFF;
  char* wp = (char*)d_ws + WP_OFF;

  hipLaunchKernelGGL(k_prep, dim3(1 + WSLOTS / 256), dim3(256), 0, stream,
                     pos, W1, W2, W3, W4, hdr, idx, wp);
  hipLaunchKernelGGL(k_mlp, dim3(NTILE_MAX), dim3(THREADS), 0, stream,
                     x, b1, b2, b3, b4, hdr, idx, wp, out);
}

// Round 9
// 64.302 us; speedup vs baseline: 1.3841x; 1.2644x over previous
//
#include <hip/hip_runtime.h>

typedef _Float16 f16;
typedef __attribute__((ext_vector_type(8))) _Float16 f16x8;
typedef __attribute__((ext_vector_type(4))) _Float16 f16x4;
typedef __attribute__((ext_vector_type(4))) float f32x4;

#define MFMA16(a, b, c) __builtin_amdgcn_mfma_f32_16x16x32_f16(a, b, c, 0, 0, 0)

#define B_N 16384
#define E_N 9
#define TILE 32
#define NTILE_MAX 520  // = 8*65
#define THREADS 512

#define D_IN 512
#define D_H1 512
#define D_H2 256
#define D_H3 128
#define D_A 16

// Weight image: per (e,w) 104 contiguous 1KB B-fragment records in exact
// consumption order. Record r at ((e*8+w)*104+r)*1024; lane l's 16B at +l*16.
#define RPW 104
#define O4B 7667712
#define WPL_BYTES 7704576
#define WSLOTS (WPL_BYTES / 16)   // 481536 = 1881 * 256

#define IDX_OFF 64
#define WP_OFF 131584
#define WS_NEED (WP_OFF + (size_t)WPL_BYTES)

// LDS (bytes) -- 48KB -> 3 blocks/CU (round-8 proven bank scheme)
#define XS_OFF 0
#define B1H_OFF 0
#define H2_OFF 16384
#define B0H_OFF 32768
#define H3_OFF 32768
#define LDS_BYTES 49152

// ---------------- bucketing (round-6 proven-fast version) ----------------

__global__ void k_bucket(const int* __restrict__ pos, int* __restrict__ hdr,
                         int* __restrict__ idx) {
  __shared__ int cnt[E_N], cur[E_N];
  __shared__ int flag_s;
  const int t = threadIdx.x;  // 1024
  if (t < E_N) cnt[t] = 0;
  if (t == 0) {
    int nz = 0;
    for (int i = 0; i < 64; ++i) nz |= pos[2 * i + 1];
    flag_s = (nz == 0) ? 1 : 0;  // int64 layout if all high words zero
  }
  __syncthreads();
  const bool f64 = flag_s != 0;
  int e[16];
#pragma unroll
  for (int k = 0; k < 16; ++k) {
    int i = k * 1024 + t;
    long long v = f64 ? ((const long long*)pos)[i] : (long long)pos[i];
    v = v < 0 ? 0 : (v > 8 ? 8 : v);
    e[k] = (int)v;
    atomicAdd(&cnt[e[k]], 1);
  }
  __syncthreads();
  if (t == 0) {
    int acc = 0;
    for (int ee = 0; ee < E_N; ++ee) { cur[ee] = acc; acc += cnt[ee]; }
  }
  if (t < E_N) hdr[8 + t] = cnt[t];
  __syncthreads();
#pragma unroll
  for (int k = 0; k < 16; ++k) {
    int i = k * 1024 + t;
    int slot = atomicAdd(&cur[e[k]], 1);
    idx[slot] = i;
  }
}

// ---------------- weight convert fp32 -> fragment-ordered fp16 image ----------------

__global__ void k_wcvt(const float* __restrict__ W1, const float* __restrict__ W2,
                       const float* __restrict__ W3, const float* __restrict__ W4,
                       char* __restrict__ wp) {
  int slot = blockIdx.x * 256 + threadIdx.x;
  if (slot >= WSLOTS) return;
  long addr = (long)slot << 4;
  int lane = slot & 63;
  int lg = lane >> 4, ln = lane & 15;
  const float* src;
  if (addr < O4B) {
    int rec = (int)(addr >> 10);
    int f = rec % RPW;
    int ew = rec / RPW;
    int w = ew & 7, e = ew >> 3;
    if (f < 64) {
      int n = w * 64 + ((f >> 5) & 1) * 32 + (f & 1) * 16 + ln;
      int k = ((f >> 2) & 7) * 64 + ((f >> 1) & 1) * 32 + lg * 8;
      src = W1 + ((long)e * D_H1 + n) * D_IN + k;
    } else if (f < 96) {
      int j = f - 64;
      int n = w * 32 + (j & 1) * 16 + ln;
      int k = (j >> 2) * 64 + ((j >> 1) & 1) * 32 + lg * 8;
      src = W2 + ((long)e * D_H2 + n) * D_H1 + k;
    } else {
      int j = f - 96;
      int n = w * 16 + ln;
      int k = (j >> 1) * 64 + (j & 1) * 32 + lg * 8;
      src = W3 + ((long)e * D_H3 + n) * D_H2 + k;
    }
  } else {
    long rel = addr - O4B;
    int e = (int)(rel >> 12);
    int r2 = (int)(rel & 4095);
    int s = r2 >> 4, n = s >> 4, k16 = s & 15;
    src = W4 + ((long)e * D_A + n) * D_H3 + k16 * 8;
  }
  float4 a = *(const float4*)src;
  float4 b = *(const float4*)(src + 4);
  f16x8 h;
  h[0] = (f16)a.x; h[1] = (f16)a.y; h[2] = (f16)a.z; h[3] = (f16)a.w;
  h[4] = (f16)b.x; h[5] = (f16)b.y; h[6] = (f16)b.z; h[7] = (f16)b.w;
  *(f16x8*)(wp + addr) = h;
}

// ---------------- fused MLP ----------------

// A-fragment (16x16x32): row m = rowoff + (l&15), k-bytes kbytes + (l>>4)*16, XOR swz
__device__ __forceinline__ f16x8 afrag(const char* base, int strideB, int rowoff,
                                       int kbytes, int lane) {
  int m = rowoff + (lane & 15);
  int q = kbytes + ((lane >> 4) * 16);
  return *(const f16x8*)(base + m * strideB + (q ^ ((m & 15) << 4)));
}

__device__ __forceinline__ f16x8 ldfrag(const char* wb, int f, int lane) {
  return *(const f16x8*)(wb + (long)f * 1024 + lane * 16);
}

__launch_bounds__(THREADS, 4)
__global__ void k_mlp(const float* __restrict__ x,
                      const float* __restrict__ b1, const float* __restrict__ b2,
                      const float* __restrict__ b3, const float* __restrict__ b4,
                      const int* __restrict__ hdr, const int* __restrict__ idx,
                      const char* __restrict__ wp, float* __restrict__ out) {
  __shared__ __align__(16) char lds[LDS_BYTES];

  int b = blockIdx.x;
  int bswz = (b & 7) * (NTILE_MAX / 8) + (b >> 3);  // bijective, 520 = 8*65

  const int* counts = hdr + 8;
  int e = -1, tile = 0, base = 0, ne = 0;
  {
    int acc = 0, off = 0;
    for (int ee = 0; ee < E_N; ++ee) {
      int n = counts[ee];
      int nt = (n + TILE - 1) / TILE;
      if (bswz < acc + nt) { e = ee; tile = bswz - acc; ne = n; base = off; break; }
      acc += nt; off += n;
    }
  }
  if (e < 0) return;
  const int rvalid = min(TILE, ne - tile * TILE);
  const int row0 = base + tile * TILE;

  const int t = threadIdx.x;
  const int lane = t & 63;
  const int wid = t >> 6;
  const int lg = lane >> 4;
  const int ln = lane & 15;

  const char* wb = wp + ((long)(e * 8 + wid) * RPW << 10);
  const char* wpe4 = wp + O4B + (long)e * 4096;

  // depth-8 prefetch queue over the flat 104-record stream
  f16x8 Q[8];
#pragma unroll
  for (int i = 0; i < 8; ++i) Q[i] = ldfrag(wb, i, lane);

  // ---- stage x tile as fp16, XOR-swizzled ----
  const float4* x4 = (const float4*)x;
  for (int u = t; u < TILE * (D_IN / 4); u += THREADS) {
    int s = u >> 7, c4 = u & 127;
    float4 v = make_float4(0.f, 0.f, 0.f, 0.f);
    if (s < rvalid) v = x4[(long)idx[row0 + s] * (D_IN / 4) + c4];
    f16x4 h;
    h[0] = (f16)v.x; h[1] = (f16)v.y; h[2] = (f16)v.z; h[3] = (f16)v.w;
    *(f16x4*)(lds + XS_OFF + s * 1024 + ((c4 * 8) ^ ((s & 15) << 4))) = h;
  }
  __syncthreads();

  // ---------------- L1: x @ W1^T -> h1 banks ----------------
  f16x8 st1[2];  // h=1 transient stage
  {
    f32x4 acc[2][2];
#pragma unroll
    for (int g = 0; g < 16; ++g) {
      const int kb = g & 7, h = g >> 3;
      if (kb == 0) {
#pragma unroll
        for (int m = 0; m < 2; ++m)
#pragma unroll
          for (int nf = 0; nf < 2; ++nf) acc[m][nf] = (f32x4){0.f, 0.f, 0.f, 0.f};
      }
      __builtin_amdgcn_s_setprio(1);
#pragma unroll
      for (int kc = 0; kc < 2; ++kc) {
        f16x8 A0 = afrag(lds + XS_OFF, 1024, 0, kb * 128 + kc * 64, lane);
        f16x8 A1 = afrag(lds + XS_OFF, 1024, 16, kb * 128 + kc * 64, lane);
#pragma unroll
        for (int nf = 0; nf < 2; ++nf) {
          const int i = g * 4 + kc * 2 + nf;
          acc[0][nf] = MFMA16(A0, Q[i & 7], acc[0][nf]);
          acc[1][nf] = MFMA16(A1, Q[i & 7], acc[1][nf]);
          Q[i & 7] = ldfrag(wb, i + 8, lane);  // i<=63 -> i+8<=71 (L2 stream)
        }
      }
      __builtin_amdgcn_s_setprio(0);
      if (kb == 7) {
        if (h == 0) {
#pragma unroll
          for (int nf = 0; nf < 2; ++nf) {
            float bias = b1[e * D_H1 + wid * 64 + nf * 16 + ln];
            int cbyte = (wid * 32 + nf * 16 + ln) * 2;
#pragma unroll
            for (int m = 0; m < 2; ++m)
#pragma unroll
              for (int j = 0; j < 4; ++j) {
                float v = acc[m][nf][j] + bias;
                v = v > 0.f ? v : 0.f;
                int rw = m * 16 + lg * 4 + j;
                *(f16*)(lds + B0H_OFF + rw * 512 + (cbyte ^ ((rw & 15) << 4))) = (f16)v;
              }
          }
        } else {
#pragma unroll
          for (int nf = 0; nf < 2; ++nf) {
            float bias = b1[e * D_H1 + wid * 64 + 32 + nf * 16 + ln];
#pragma unroll
            for (int m = 0; m < 2; ++m)
#pragma unroll
              for (int j = 0; j < 4; ++j) {
                float v = acc[m][nf][j] + bias;
                st1[m][nf * 4 + j] = (f16)(v > 0.f ? v : 0.f);
              }
          }
        }
      }
    }
  }
  __syncthreads();  // all L1 reads of x done; x region dead

  // write h=1 half into bank1 (overlays x bytes 0..16K)
#pragma unroll
  for (int m = 0; m < 2; ++m)
#pragma unroll
    for (int nf = 0; nf < 2; ++nf) {
      int cbyte = (wid * 32 + nf * 16 + ln) * 2;
#pragma unroll
      for (int j = 0; j < 4; ++j) {
        int rw = m * 16 + lg * 4 + j;
        *(f16*)(lds + B1H_OFF + rw * 512 + (cbyte ^ ((rw & 15) << 4))) =
            st1[m][nf * 4 + j];
      }
    }
  __syncthreads();

  // ---------------- L2: h1 @ W2^T (frags 64..95) ----------------
  {
    f32x4 acc[2][2];
#pragma unroll
    for (int m = 0; m < 2; ++m)
#pragma unroll
      for (int nf = 0; nf < 2; ++nf) acc[m][nf] = (f32x4){0.f, 0.f, 0.f, 0.f};
#pragma unroll
    for (int g = 0; g < 8; ++g) {
      __builtin_amdgcn_s_setprio(1);
#pragma unroll
      for (int kc = 0; kc < 2; ++kc) {
        const char* bank = lds + (kc ? B1H_OFF : B0H_OFF);
        f16x8 A0 = afrag(bank, 512, 0, g * 64, lane);
        f16x8 A1 = afrag(bank, 512, 16, g * 64, lane);
#pragma unroll
        for (int nf = 0; nf < 2; ++nf) {
          const int i = 64 + g * 4 + kc * 2 + nf;
          acc[0][nf] = MFMA16(A0, Q[i & 7], acc[0][nf]);
          acc[1][nf] = MFMA16(A1, Q[i & 7], acc[1][nf]);
          if (i < 96) Q[i & 7] = ldfrag(wb, i + 8, lane);  // up to frag 103
        }
      }
      __builtin_amdgcn_s_setprio(0);
    }
#pragma unroll
    for (int nf = 0; nf < 2; ++nf) {
      float bias = b2[e * D_H2 + wid * 32 + nf * 16 + ln];
      int cbyte = (wid * 32 + nf * 16 + ln) * 2;
#pragma unroll
      for (int m = 0; m < 2; ++m)
#pragma unroll
        for (int j = 0; j < 4; ++j) {
          float v = acc[m][nf][j] + bias;
          v = v > 0.f ? v : 0.f;
          int rw = m * 16 + lg * 4 + j;
          *(f16*)(lds + H2_OFF + rw * 512 + (cbyte ^ ((rw & 15) << 4))) = (f16)v;
        }
    }
  }
  __syncthreads();

  // ---------------- L3: h2 @ W3^T (frags 96..103, all preloaded) ----------------
  {
    f32x4 acc3[2];
    acc3[0] = (f32x4){0.f, 0.f, 0.f, 0.f};
    acc3[1] = (f32x4){0.f, 0.f, 0.f, 0.f};
#pragma unroll
    for (int g = 0; g < 4; ++g) {
      __builtin_amdgcn_s_setprio(1);
#pragma unroll
      for (int kc = 0; kc < 2; ++kc) {
        const int i = 96 + g * 2 + kc;
        f16x8 A0 = afrag(lds + H2_OFF, 512, 0, g * 128 + kc * 64, lane);
        f16x8 A1 = afrag(lds + H2_OFF, 512, 16, g * 128 + kc * 64, lane);
        acc3[0] = MFMA16(A0, Q[i & 7], acc3[0]);
        acc3[1] = MFMA16(A1, Q[i & 7], acc3[1]);
      }
      __builtin_amdgcn_s_setprio(0);
    }
    int n = wid * 16 + ln;
    float bias = b3[e * D_H3 + n];
#pragma unroll
    for (int m = 0; m < 2; ++m)
#pragma unroll
      for (int j = 0; j < 4; ++j) {
        float v = acc3[m][j] + bias;
        v = v > 0.f ? v : 0.f;
        int rw = m * 16 + lg * 4 + j;
        *(f16*)(lds + H3_OFF + rw * 256 + ((n * 2) ^ ((rw & 15) << 4))) = (f16)v;
      }
  }
  __syncthreads();

  // ---------------- L4 + softmax (waves 0,1) ----------------
  if (wid < 2) {
    f32x4 a4 = (f32x4){0.f, 0.f, 0.f, 0.f};
#pragma unroll
    for (int kc = 0; kc < 4; ++kc) {
      f16x8 Bv = *(const f16x8*)(wpe4 + ln * 256 + kc * 64 + lg * 16);
      f16x8 Av = afrag(lds + H3_OFF, 256, wid * 16, kc * 64, lane);
      a4 = MFMA16(Av, Bv, a4);
    }
    float bias = b4[e * D_A + ln];
#pragma unroll
    for (int j = 0; j < 4; ++j) {
      float v = a4[j] + bias;
      float mx = v;
      for (int msk = 8; msk >= 1; msk >>= 1) mx = fmaxf(mx, __shfl_xor(mx, msk));
      float pe = expf(v - mx);
      float sm = pe;
      for (int msk = 8; msk >= 1; msk >>= 1) sm += __shfl_xor(sm, msk);
      int rl = wid * 16 + lg * 4 + j;
      if (rl < rvalid) out[(long)idx[row0 + rl] * D_A + ln] = pe / sm;
    }
  }
}

// ---------------- host ----------------

extern "C" void kernel_launch(void* const* d_in, const int* in_sizes, int n_in,
                              void* d_out, int out_size, void* d_ws, size_t ws_size,
                              hipStream_t stream) {
  const float* x  = (const float*)d_in[0];
  const int* pos  = (const int*)d_in[1];
  const float* W1 = (const float*)d_in[2];
  const float* b1 = (const float*)d_in[3];
  const float* W2 = (const float*)d_in[4];
  const float* b2 = (const float*)d_in[5];
  const float* W3 = (const float*)d_in[6];
  const float* b3 = (const float*)d_in[7];
  const float* W4 = (const float*)d_in[8];
  const float* b4 = (const float*)d_in[9];
  float* out = (float*)d_out;

  int* hdr = (int*)d_ws;
  int* idx = hdr + IDX_OFF;
  char* wp = (char*)d_ws + WP_OFF;

  hipLaunchKernelGGL(k_bucket, dim3(1), dim3(1024), 0, stream, pos, hdr, idx);
  hipLaunchKernelGGL(k_wcvt, dim3(WSLOTS / 256), dim3(256), 0, stream,
                     W1, W2, W3, W4, wp);
  hipLaunchKernelGGL(k_mlp, dim3(NTILE_MAX), dim3(THREADS), 0, stream,
                     x, b1, b2, b3, b4, hdr, idx, wp, out);
}

// Round 10
// 60.058 us; speedup vs baseline: 1.4819x; 1.0707x over previous
//
#include <hip/hip_runtime.h>

typedef _Float16 f16;
typedef __attribute__((ext_vector_type(8))) _Float16 f16x8;
typedef __attribute__((ext_vector_type(4))) _Float16 f16x4;
typedef __attribute__((ext_vector_type(4))) float f32x4;

#define MFMA16(a, b, c) __builtin_amdgcn_mfma_f32_16x16x32_f16(a, b, c, 0, 0, 0)

#define B_N 16384
#define E_N 9
#define TILE 48
#define NT_GRID 352   // 8*44 >= max tiles (341+9); exact XCD swizzle
#define THREADS 512

#define D_IN 512
#define D_H1 512
#define D_H2 256
#define D_H3 128
#define D_A 16

// Weight image: per (e,w) 104 contiguous 1KB B-fragment records, k-major order.
// Record r at ((e*8+w)*104+r)*1024; lane l's 16B at +l*16; lane holds (n,k[8]).
//   r<64  (L1): kk=r>>2, nf=r&3:  n=w*64+nf*16+ln, k=kk*32+lg*8   (W1: 512x512)
//   64..95(L2): j=r-64,kk=j>>1,nf=j&1: n=w*32+nf*16+ln, k=kk*32+lg*8 (W2: 256x512)
//   96..103(L3): kk=r-96:         n=w*16+ln,       k=kk*32+lg*8   (W3: 128x256)
// L4: plain [16n][128k] per expert (4KB) at O4B.
#define RPW 104
#define O4B 7667712
#define WPL_BYTES 7704576
#define WSLOTS (WPL_BYTES / 16)

#define IDX_OFF 64
#define WP_OFF 131584
#define WS_NEED (WP_OFF + (size_t)WPL_BYTES)

// LDS (bytes) -- 72KB -> 2 blocks/CU.
// x/h1 [48][1024B] at 0..48K (swz (row&15)<<4); h1 overwrites x after L1.
// h2   [48][512B]  at 48K..72K (dedicated).
// h3   [48][256B]  at 0..12K (overlays x/h1 after L2 barrier).
#define H2_OFF 49152
#define LDS_BYTES 73728

// ---------------- bucketing (proven-fast) ----------------

__global__ void k_bucket(const int* __restrict__ pos, int* __restrict__ hdr,
                         int* __restrict__ idx) {
  __shared__ int cnt[E_N], cur[E_N];
  __shared__ int flag_s;
  const int t = threadIdx.x;  // 1024
  if (t < E_N) cnt[t] = 0;
  if (t == 0) {
    int nz = 0;
    for (int i = 0; i < 64; ++i) nz |= pos[2 * i + 1];
    flag_s = (nz == 0) ? 1 : 0;  // int64 layout if all high words zero
  }
  __syncthreads();
  const bool f64 = flag_s != 0;
  int e[16];
#pragma unroll
  for (int k = 0; k < 16; ++k) {
    int i = k * 1024 + t;
    long long v = f64 ? ((const long long*)pos)[i] : (long long)pos[i];
    v = v < 0 ? 0 : (v > 8 ? 8 : v);
    e[k] = (int)v;
    atomicAdd(&cnt[e[k]], 1);
  }
  __syncthreads();
  if (t == 0) {
    int acc = 0;
    for (int ee = 0; ee < E_N; ++ee) { cur[ee] = acc; acc += cnt[ee]; }
  }
  if (t < E_N) hdr[8 + t] = cnt[t];
  __syncthreads();
#pragma unroll
  for (int k = 0; k < 16; ++k) {
    int i = k * 1024 + t;
    int slot = atomicAdd(&cur[e[k]], 1);
    idx[slot] = i;
  }
}

// ---------------- weight convert fp32 -> k-major fragment image ----------------

__global__ void k_wcvt(const float* __restrict__ W1, const float* __restrict__ W2,
                       const float* __restrict__ W3, const float* __restrict__ W4,
                       char* __restrict__ wp) {
  int slot = blockIdx.x * 256 + threadIdx.x;
  if (slot >= WSLOTS) return;
  long addr = (long)slot << 4;
  int lane = slot & 63;
  int lg = lane >> 4, ln = lane & 15;
  const float* src;
  if (addr < O4B) {
    int rec = (int)(addr >> 10);
    int f = rec % RPW;
    int ew = rec / RPW;
    int w = ew & 7, e = ew >> 3;
    if (f < 64) {
      int kk = f >> 2, nf = f & 3;
      int n = w * 64 + nf * 16 + ln;
      int k = kk * 32 + lg * 8;
      src = W1 + ((long)e * D_H1 + n) * D_IN + k;
    } else if (f < 96) {
      int j = f - 64;
      int kk = j >> 1, nf = j & 1;
      int n = w * 32 + nf * 16 + ln;
      int k = kk * 32 + lg * 8;
      src = W2 + ((long)e * D_H2 + n) * D_H1 + k;
    } else {
      int kk = f - 96;
      int n = w * 16 + ln;
      int k = kk * 32 + lg * 8;
      src = W3 + ((long)e * D_H3 + n) * D_H2 + k;
    }
  } else {
    long rel = addr - O4B;
    int e = (int)(rel >> 12);
    int r2 = (int)(rel & 4095);
    int s = r2 >> 4, n = s >> 4, k16 = s & 15;
    src = W4 + ((long)e * D_A + n) * D_H3 + k16 * 8;
  }
  float4 a = *(const float4*)src;
  float4 b = *(const float4*)(src + 4);
  f16x8 h;
  h[0] = (f16)a.x; h[1] = (f16)a.y; h[2] = (f16)a.z; h[3] = (f16)a.w;
  h[4] = (f16)b.x; h[5] = (f16)b.y; h[6] = (f16)b.z; h[7] = (f16)b.w;
  *(f16x8*)(wp + addr) = h;
}

// ---------------- fused MLP ----------------

__device__ __forceinline__ f16x8 afrag(const char* base, int strideB, int rowoff,
                                       int kbytes, int lane) {
  int m = rowoff + (lane & 15);
  int q = kbytes + ((lane >> 4) * 16);
  return *(const f16x8*)(base + m * strideB + (q ^ ((m & 15) << 4)));
}

__device__ __forceinline__ f16x8 ldfrag(const char* wb, int f, int lane) {
  return *(const f16x8*)(wb + (long)f * 1024 + lane * 16);
}

__launch_bounds__(THREADS, 4)  // cap 128 regs; audited demand ~107
__global__ void k_mlp(const float* __restrict__ x,
                      const float* __restrict__ b1, const float* __restrict__ b2,
                      const float* __restrict__ b3, const float* __restrict__ b4,
                      const int* __restrict__ hdr, const int* __restrict__ idx,
                      const char* __restrict__ wp, float* __restrict__ out) {
  __shared__ __align__(16) char lds[LDS_BYTES];

  int b = blockIdx.x;
  int bswz = (b & 7) * (NT_GRID / 8) + (b >> 3);  // bijective on [0,352)

  const int* counts = hdr + 8;
  int e = -1, tile = 0, base = 0, ne = 0;
  {
    int acc = 0, off = 0;
    for (int ee = 0; ee < E_N; ++ee) {
      int n = counts[ee];
      int nt = (n + TILE - 1) / TILE;
      if (bswz < acc + nt) { e = ee; tile = bswz - acc; ne = n; base = off; break; }
      acc += nt; off += n;
    }
  }
  if (e < 0) return;
  const int rvalid = min(TILE, ne - tile * TILE);
  const int row0 = base + tile * TILE;

  const int t = threadIdx.x;
  const int lane = t & 63;
  const int wid = t >> 6;
  const int lg = lane >> 4;
  const int ln = lane & 15;

  const char* wb = wp + ((long)(e * 8 + wid) * RPW << 10);
  const char* wpe4 = wp + O4B + (long)e * 4096;

  // depth-8 queue over the flat 104-record k-major stream
  f16x8 Q[8];
#pragma unroll
  for (int i = 0; i < 8; ++i) Q[i] = ldfrag(wb, i, lane);

  // ---- stage x tile (48 rows) as fp16, XOR-swizzled ----
  const float4* x4 = (const float4*)x;
#pragma unroll
  for (int v8 = 0; v8 < 12; ++v8) {
    int u = v8 * THREADS + t;              // 6144 = 48*128 float4s
    int s = u >> 7, c4 = u & 127;
    float4 v = make_float4(0.f, 0.f, 0.f, 0.f);
    if (s < rvalid) v = x4[(long)idx[row0 + s] * (D_IN / 4) + c4];
    f16x4 h;
    h[0] = (f16)v.x; h[1] = (f16)v.y; h[2] = (f16)v.z; h[3] = (f16)v.w;
    *(f16x4*)(lds + s * 1024 + ((c4 * 8) ^ ((s & 15) << 4))) = h;
  }
  __syncthreads();

  // ---------------- L1: h1[48x512] = x @ W1^T (recs 0..63, kk=ss) ----------------
  {
    f32x4 acc1[3][4];
#pragma unroll
    for (int m = 0; m < 3; ++m)
#pragma unroll
      for (int r = 0; r < 4; ++r) acc1[m][r] = (f32x4){0.f, 0.f, 0.f, 0.f};

#pragma unroll
    for (int ss = 0; ss < 16; ++ss) {
      f16x8 A0 = afrag(lds, 1024, 0, ss * 64, lane);
      f16x8 A1 = afrag(lds, 1024, 16, ss * 64, lane);
      f16x8 A2 = afrag(lds, 1024, 32, ss * 64, lane);
      __builtin_amdgcn_s_setprio(1);
#pragma unroll
      for (int r = 0; r < 4; ++r) {
        const int i = ss * 4 + r;
        acc1[0][r] = MFMA16(A0, Q[i & 7], acc1[0][r]);
        acc1[1][r] = MFMA16(A1, Q[i & 7], acc1[1][r]);
        acc1[2][r] = MFMA16(A2, Q[i & 7], acc1[2][r]);
        Q[i & 7] = ldfrag(wb, i + 8, lane);  // i<=63 -> i+8<=71
      }
      __builtin_amdgcn_s_setprio(0);
      __builtin_amdgcn_sched_barrier(0);
    }
    __syncthreads();  // all L1 reads of x done; x region dead

    // write h1 = relu(acc+bias) into x region [48][1024B]
#pragma unroll
    for (int nf = 0; nf < 4; ++nf) {
      int n = wid * 64 + nf * 16 + ln;
      float bias = b1[e * D_H1 + n];
#pragma unroll
      for (int m = 0; m < 3; ++m)
#pragma unroll
        for (int j = 0; j < 4; ++j) {
          float v = acc1[m][nf][j] + bias;
          v = v > 0.f ? v : 0.f;
          int rw = m * 16 + lg * 4 + j;
          *(f16*)(lds + rw * 1024 + ((n * 2) ^ ((rw & 15) << 4))) = (f16)v;
        }
    }
  }
  __syncthreads();

  // ---------------- L2: h2[48x256] = h1 @ W2^T (recs 64..95) ----------------
  {
    f32x4 acc2[3][2];
#pragma unroll
    for (int m = 0; m < 3; ++m)
#pragma unroll
      for (int nf = 0; nf < 2; ++nf) acc2[m][nf] = (f32x4){0.f, 0.f, 0.f, 0.f};

#pragma unroll
    for (int ss = 16; ss < 24; ++ss) {
#pragma unroll
      for (int hh = 0; hh < 2; ++hh) {
        const int kk = (ss - 16) * 2 + hh;
        f16x8 A0 = afrag(lds, 1024, 0, kk * 64, lane);
        f16x8 A1 = afrag(lds, 1024, 16, kk * 64, lane);
        f16x8 A2 = afrag(lds, 1024, 32, kk * 64, lane);
        __builtin_amdgcn_s_setprio(1);
#pragma unroll
        for (int nf = 0; nf < 2; ++nf) {
          const int i = ss * 4 + hh * 2 + nf;  // = 64 + kk*2 + nf
          acc2[0][nf] = MFMA16(A0, Q[i & 7], acc2[0][nf]);
          acc2[1][nf] = MFMA16(A1, Q[i & 7], acc2[1][nf]);
          acc2[2][nf] = MFMA16(A2, Q[i & 7], acc2[2][nf]);
          if (i < 96) Q[i & 7] = ldfrag(wb, i + 8, lane);  // up to rec 103
        }
        __builtin_amdgcn_s_setprio(0);
      }
      __builtin_amdgcn_sched_barrier(0);
    }
    // h2 region is dedicated: direct write, no pre-barrier
#pragma unroll
    for (int nf = 0; nf < 2; ++nf) {
      int n = wid * 32 + nf * 16 + ln;
      float bias = b2[e * D_H2 + n];
#pragma unroll
      for (int m = 0; m < 3; ++m)
#pragma unroll
        for (int j = 0; j < 4; ++j) {
          float v = acc2[m][nf][j] + bias;
          v = v > 0.f ? v : 0.f;
          int rw = m * 16 + lg * 4 + j;
          *(f16*)(lds + H2_OFF + rw * 512 + ((n * 2) ^ ((rw & 15) << 4))) = (f16)v;
        }
    }
  }
  __syncthreads();

  // ---------------- L3: h3[48x128] = h2 @ W3^T (recs 96..103, in Q) ----------------
  {
    f32x4 acc3[3];
#pragma unroll
    for (int m = 0; m < 3; ++m) acc3[m] = (f32x4){0.f, 0.f, 0.f, 0.f};
    __builtin_amdgcn_s_setprio(1);
#pragma unroll
    for (int kk = 0; kk < 8; ++kk) {
      const int i = 96 + kk;
      f16x8 A0 = afrag(lds + H2_OFF, 512, 0, kk * 64, lane);
      f16x8 A1 = afrag(lds + H2_OFF, 512, 16, kk * 64, lane);
      f16x8 A2 = afrag(lds + H2_OFF, 512, 32, kk * 64, lane);
      acc3[0] = MFMA16(A0, Q[i & 7], acc3[0]);
      acc3[1] = MFMA16(A1, Q[i & 7], acc3[1]);
      acc3[2] = MFMA16(A2, Q[i & 7], acc3[2]);
    }
    __builtin_amdgcn_s_setprio(0);
    int n = wid * 16 + ln;
    float bias = b3[e * D_H3 + n];
    // h3 [48][256B] at offset 0 (h1 dead after L2's barrier)
#pragma unroll
    for (int m = 0; m < 3; ++m)
#pragma unroll
      for (int j = 0; j < 4; ++j) {
        float v = acc3[m][j] + bias;
        v = v > 0.f ? v : 0.f;
        int rw = m * 16 + lg * 4 + j;
        *(f16*)(lds + rw * 256 + ((n * 2) ^ ((rw & 15) << 4))) = (f16)v;
      }
  }
  __syncthreads();

  // ---------------- L4 + softmax (waves 0..2, 16 rows each) ----------------
  if (wid < 3) {
    f32x4 a4 = (f32x4){0.f, 0.f, 0.f, 0.f};
#pragma unroll
    for (int kc = 0; kc < 4; ++kc) {
      f16x8 Bv = *(const f16x8*)(wpe4 + ln * 256 + kc * 64 + lg * 16);
      f16x8 Av = afrag(lds, 256, wid * 16, kc * 64, lane);
      a4 = MFMA16(Av, Bv, a4);
    }
    float bias = b4[e * D_A + ln];
#pragma unroll
    for (int j = 0; j < 4; ++j) {
      float v = a4[j] + bias;
      float mx = v;
      for (int msk = 8; msk >= 1; msk >>= 1) mx = fmaxf(mx, __shfl_xor(mx, msk));
      float pe = expf(v - mx);
      float sm = pe;
      for (int msk = 8; msk >= 1; msk >>= 1) sm += __shfl_xor(sm, msk);
      int rl = wid * 16 + lg * 4 + j;
      if (rl < rvalid) out[(long)idx[row0 + rl] * D_A + ln] = pe / sm;
    }
  }
}

// ---------------- host ----------------

extern "C" void kernel_launch(void* const* d_in, const int* in_sizes, int n_in,
                              void* d_out, int out_size, void* d_ws, size_t ws_size,
                              hipStream_t stream) {
  const float* x  = (const float*)d_in[0];
  const int* pos  = (const int*)d_in[1];
  const float* W1 = (const float*)d_in[2];
  const float* b1 = (const float*)d_in[3];
  const float* W2 = (const float*)d_in[4];
  const float* b2 = (const float*)d_in[5];
  const float* W3 = (const float*)d_in[6];
  const float* b3 = (const float*)d_in[7];
  const float* W4 = (const float*)d_in[8];
  const float* b4 = (const float*)d_in[9];
  float* out = (float*)d_out;

  int* hdr = (int*)d_ws;
  int* idx = hdr + IDX_OFF;
  char* wp = (char*)d_ws + WP_OFF;

  hipLaunchKernelGGL(k_bucket, dim3(1), dim3(1024), 0, stream, pos, hdr, idx);
  hipLaunchKernelGGL(k_wcvt, dim3(WSLOTS / 256), dim3(256), 0, stream,
                     W1, W2, W3, W4, wp);
  hipLaunchKernelGGL(k_mlp, dim3(NT_GRID), dim3(THREADS), 0, stream,
                     x, b1, b2, b3, b4, hdr, idx, wp, out);
}